// Round 6
// baseline (214.487 us; speedup 1.0000x reference)
//
#include <hip/hip_runtime.h>

// ExtendedKalmanFilter: T=64, B=32768, D=6, O=3, U=6.
//
// cov0 is broadcast(0.1*I) and A,Bm,Q,C,R are shared => covariance/gain
// recursion is batch-independent. Per-step affine coefficients
// mean_{t+1} = M_t mean_t + N_t u_t + K_t z_t; chunk transitions
// G_c = M_{c*8+7}...M_{c*8}. Mean recurrence solved as chunked scan.
//
// Round-6 change (single variable vs round-5): the per-block redundant
// recursion runs on wave wsel = ((lb>>3)^(lb>>8))&3 instead of wave 0.
// Round-5 post-mortem: gfused=78us vs 46us solo recursion = 1.7x ~= 4x0.4
// issue-slot demand -> all four co-resident blocks' wave 0 landed on the
// SAME SIMD (SPI deals each block's waves starting at SIMD 0), stacking
// four latency-bound recursion waves on one SIMD while 3 SIMDs idled at
// the barrier. The XOR hash gives 4 distinct wsel for co-resident blocks
// under BOTH plausible dispatch patterns (stride-8 fill / stride-256
// round-robin), so recursion waves spread across the 4 SIMDs.
// Recursion math / LDS layout / gpass / opass / launcher are round-5
// verbatim => outputs bit-identical (absmax 0.0625).

#define T_STEPS 64
#define BATCH   32768
#define NCOEF   90   // per-step: M(36) + N(36) + K(18)
#define NCHUNK  8
#define CLEN    8

#define G_OFF   23040                      // bytes: after coef[64*90]
#define GV_OFF  24192                      // bytes: after Gmat[8*36]
#define WS_NEED (GV_OFF + NCHUNK * BATCH * 6 * 4)

__device__ __forceinline__ float rdlane(float v, int lane) {
    return __int_as_float(__builtin_amdgcn_readlane(__float_as_int(v), lane));
}

// Single-wave LDS producer->consumer ordering: drain LDS ops, pin program
// order. Valid only when all communicating lanes are in ONE wave.
__device__ __forceinline__ void wave_lds_sync() {
    asm volatile("s_waitcnt lgkmcnt(0)" ::: "memory");
    __builtin_amdgcn_wave_barrier();
}

// ---- fused: per-chunk redundant recursion (1 wave) + prefetch + gpass ----
__global__ __launch_bounds__(256, 4) void ekf_gfused(
    const float* __restrict__ z, const float* __restrict__ u,
    const float* __restrict__ cov0, const float* __restrict__ Ag,
    const float* __restrict__ Bg,   const float* __restrict__ Qtg,
    const float* __restrict__ Cg,   const float* __restrict__ Rtg,
    float* __restrict__ coef, float* __restrict__ Gmat,
    float* __restrict__ g)
{
    __shared__ float sA[36], sB[36], sC[18], sQt[36], sRt[9];
    __shared__ float Qc[36], Rc[9];
    __shared__ float Mall[T_STEPS * 36];       // only used by the writeAll block
    __shared__ float scoef[CLEN * NCOEF];      // this chunk's coefficients

    const int tid  = threadIdx.x;
    const int lane = tid & 63;
    const int wave = tid >> 6;
    const int c    = blockIdx.y;
    const int bx   = blockIdx.x;
    const int b    = bx * 256 + tid;
    const int lb   = c * gridDim.x + bx;                 // linear block id
    const int wsel = ((lb >> 3) ^ (lb >> 8)) & 3;        // recursion wave
    const bool writeAll = (bx == 0 && c == NCHUNK - 1);
    const int tEnd = (c + 1) * CLEN;

    // ---- setup with ALL waves participating in the barriers ----
    if (tid < 36) { sA[tid] = Ag[tid]; sB[tid] = Bg[tid]; sQt[tid] = Qtg[tid]; }
    if (tid < 18) sC[tid] = Cg[tid];
    if (tid < 9)  sRt[tid] = Rtg[tid];
    __syncthreads();

    if (tid < 36) {                        // Qc = Qt Qt^T  (round-0 order)
        int i = tid / 6, j = tid % 6; float s = 0.f;
        #pragma unroll
        for (int k = 0; k < 6; ++k) s += sQt[i*6+k] * sQt[j*6+k];
        Qc[tid] = s;
    } else if (tid < 45) {                 // Rc = Rt Rt^T
        int q = tid - 36, i = q / 3, j = q % 3; float s = 0.f;
        #pragma unroll
        for (int k = 0; k < 3; ++k) s += sRt[i*3+k] * sRt[j*3+k];
        Rc[q] = s;
    }
    __syncthreads();

    if (wave == wsel) {
        // ============ recursion wave: round-0 verbatim, indexed by lane ====
        const int i6 = lane / 6, j6 = lane % 6;
        const int i3 = lane / 3, j3 = lane % 3;
        const int qS = (lane >= 36 && lane < 45) ? lane - 36 : 0;
        const int sa = qS / 3, sb = qS % 3;

        float Ai[6], Aj[6], Acol[6], Bcol[6], Cst[18], Crow[6], Ca[6];
        float qcv = 0.f, rcv = 0.f;
        #pragma unroll
        for (int l = 0; l < 6; ++l) { Ai[l]=0.f; Aj[l]=0.f; Acol[l]=0.f; Bcol[l]=0.f; Crow[l]=0.f; Ca[l]=0.f; }
        #pragma unroll
        for (int l = 0; l < 18; ++l) Cst[l] = 0.f;

        if (lane < 36) {
            #pragma unroll
            for (int l = 0; l < 6; ++l) {
                Ai[l] = sA[i6*6+l]; Aj[l] = sA[j6*6+l];
                Acol[l] = sA[l*6+j6]; Bcol[l] = sB[l*6+j6];
            }
            #pragma unroll
            for (int l = 0; l < 18; ++l) Cst[l] = sC[l];
            qcv = Qc[lane];
        }
        if (lane < 18) {
            #pragma unroll
            for (int l = 0; l < 6; ++l) Crow[l] = sC[j3*6+l];
        }
        if (lane >= 36 && lane < 45) {
            #pragma unroll
            for (int l = 0; l < 6; ++l) Ca[l] = sC[sa*6+l];
            rcv = Rc[qS];
        }

        float Preg = 0.f;                  // lanes 0..35 own P[i6][j6]
        if (lane < 36) Preg = cov0[lane];
        wave_lds_sync();

        for (int t = 0; t < tEnd; ++t) {
            // ---- stage A: P1 = A P A^T + Qc (round-0 verbatim) ----
            float Pf[36];
            #pragma unroll
            for (int e = 0; e < 36; ++e) Pf[e] = rdlane(Preg, e);
            float p1 = qcv;
            #pragma unroll
            for (int k = 0; k < 6; ++k) {
                float tmp = 0.f;
                #pragma unroll
                for (int l = 0; l < 6; ++l) tmp += Pf[k*6+l] * Aj[l];
                p1 += Ai[k] * tmp;
            }

            // ---- stage B1: PCt (lanes 0..17) ----
            float p1r[6];
            #pragma unroll
            for (int l = 0; l < 6; ++l) p1r[l] = __shfl(p1, i3*6 + l);
            float pct = p1r[0]*Crow[0] + p1r[1]*Crow[1] + p1r[2]*Crow[2]
                      + p1r[3]*Crow[3] + p1r[4]*Crow[4] + p1r[5]*Crow[5];

            // ---- stage B2: S (lanes 36..44) ----
            float sv = rcv;
            #pragma unroll
            for (int l = 0; l < 6; ++l) sv += Ca[l] * __shfl(pct, l*3 + sb);

            // ---- stage C: inv(S), K, IKC, M/N/Pnext (round-0 verbatim) ----
            float Sa = rdlane(sv, 36), Sb = rdlane(sv, 37), Sc = rdlane(sv, 38);
            float Sd = rdlane(sv, 39), Se = rdlane(sv, 40), Sf = rdlane(sv, 41);
            float Sg = rdlane(sv, 42), Sh = rdlane(sv, 43), Si = rdlane(sv, 44);
            float idet = 1.0f / (Sa*(Se*Si-Sf*Sh) - Sb*(Sd*Si-Sf*Sg) + Sc*(Sd*Sh-Se*Sg));
            float s0 =  (Se*Si-Sf*Sh)*idet, s1 = -(Sb*Si-Sc*Sh)*idet, s2 =  (Sb*Sf-Sc*Se)*idet;
            float s3 = -(Sd*Si-Sf*Sg)*idet, s4 =  (Sa*Si-Sc*Sg)*idet, s5 = -(Sa*Sf-Sc*Sd)*idet;
            float s6 =  (Sd*Sh-Se*Sg)*idet, s7 = -(Sa*Sh-Sb*Sg)*idet, s8 =  (Sa*Se-Sb*Sd)*idet;

            float Pi0 = __shfl(pct, i6*3 + 0);
            float Pi1 = __shfl(pct, i6*3 + 1);
            float Pi2 = __shfl(pct, i6*3 + 2);
            float K0 = Pi0*s0 + Pi1*s3 + Pi2*s6;
            float K1 = Pi0*s1 + Pi1*s4 + Pi2*s7;
            float K2 = Pi0*s2 + Pi1*s5 + Pi2*s8;

            float ik[6];
            #pragma unroll
            for (int k = 0; k < 6; ++k)
                ik[k] = ((i6 == k) ? 1.f : 0.f)
                      - (K0*Cst[0*6+k] + K1*Cst[1*6+k] + K2*Cst[2*6+k]);

            float p1col[6];
            #pragma unroll
            for (int k = 0; k < 6; ++k) p1col[k] = __shfl(p1, k*6 + j6);

            float mo = 0.f, no = 0.f, pn = 0.f;
            #pragma unroll
            for (int k = 0; k < 6; ++k) {
                mo += ik[k] * Acol[k];
                no += ik[k] * Bcol[k];
                pn += ik[k] * p1col[k];
            }

            if (lane < 36) {
                if (t >= c * CLEN) {                 // my chunk -> LDS
                    const int ts = t - c * CLEN;
                    scoef[ts*NCOEF + lane]      = mo;
                    scoef[ts*NCOEF + 36 + lane] = no;
                    if (j6 < 3)
                        scoef[ts*NCOEF + 72 + i6*3 + j6] =
                            (j6 == 0 ? K0 : (j6 == 1 ? K1 : K2));
                }
                if (writeAll) {                      // writeAll block: global log
                    coef[t*NCOEF + lane]      = mo;
                    coef[t*NCOEF + 36 + lane] = no;
                    if (j6 < 3)
                        coef[t*NCOEF + 72 + i6*3 + j6] =
                            (j6 == 0 ? K0 : (j6 == 1 ? K1 : K2));
                    Mall[t*36 + lane] = mo;
                }
            }
            Preg = pn;
        }

        // ---- G-product phase (writeAll block only; round-0 verbatim) ----
        if (writeAll) {
            wave_lds_sync();                         // drain Mall writes
            const int im = (lane < 36) ? i6 : 0;
            for (int cch = 0; cch < NCHUNK; ++cch) {
                float Gv = (lane < 36) ? Mall[(cch*CLEN)*36 + lane] : 0.f;
                for (int s = 1; s < CLEN; ++s) {
                    float acc = 0.f;
                    #pragma unroll
                    for (int k = 0; k < 6; ++k) {
                        float gk = __shfl(Gv, k*6 + j6);
                        acc += Mall[(cch*CLEN + s)*36 + im*6 + k] * gk;
                    }
                    Gv = acc;
                }
                if (lane < 36) Gmat[cch*36 + lane] = Gv;
            }
        }
    } else {
        // ============ other 3 waves: prefetch this block's z/u slice =======
        float acc = 0.f;
        #pragma unroll
        for (int s = 0; s < CLEN; ++s) {
            const int base = (c * CLEN + s) * BATCH + b;
            const float*  zp = z + (size_t)base * 3;
            const float2* up = (const float2*)(u + (size_t)base * 6);
            acc += zp[0] + zp[1] + zp[2];
            float2 a0 = up[0], a1 = up[1], a2 = up[2];
            acc += a0.x + a0.y + a1.x + a1.y + a2.x + a2.y;
        }
        if (wave == ((wsel + 1) & 3)) {    // cover the recursion wave's range
            const int b2 = bx * 256 + (wsel << 6) + lane;
            #pragma unroll
            for (int s = 0; s < CLEN; ++s) {
                const int base = (c * CLEN + s) * BATCH + b2;
                const float*  zp = z + (size_t)base * 3;
                const float2* up = (const float2*)(u + (size_t)base * 6);
                acc += zp[0] + zp[1] + zp[2];
                float2 a0 = up[0], a1 = up[1], a2 = up[2];
                acc += a0.x + a0.y + a1.x + a1.y + a2.x + a2.y;
            }
        }
        asm volatile("" :: "v"(acc));      // keep prefetch alive, discard
    }

    __syncthreads();                       // scoef ready for all waves

    // ================= gpass (round-0 verbatim math, coef from LDS) ========
    {
        float m[6] = {0.f, 0.f, 0.f, 0.f, 0.f, 0.f};

        #pragma unroll
        for (int s = 0; s < CLEN; ++s) {
            const int base = (c * CLEN + s) * BATCH + b;

            const float*  zp = z + (size_t)base * 3;
            const float2* up = (const float2*)(u + (size_t)base * 6);
            float zz[3] = { zp[0], zp[1], zp[2] };
            float2 u01 = up[0], u23 = up[1], u45 = up[2];
            float uu[6] = { u01.x, u01.y, u23.x, u23.y, u45.x, u45.y };

            float nm[6];
            #pragma unroll
            for (int i = 0; i < 6; ++i) {           // round-0 accumulation order
                float s2 = 0.f;
                #pragma unroll
                for (int j = 0; j < 6; ++j) s2 += scoef[s*NCOEF + i*6 + j] * m[j];
                #pragma unroll
                for (int j = 0; j < 6; ++j) s2 += scoef[s*NCOEF + 36 + i*6 + j] * uu[j];
                #pragma unroll
                for (int j = 0; j < 3; ++j) s2 += scoef[s*NCOEF + 72 + i*3 + j] * zz[j];
                nm[i] = s2;
            }
            #pragma unroll
            for (int i = 0; i < 6; ++i) m[i] = nm[i];
        }

        float2* gp = (float2*)(g + ((size_t)c * BATCH + b) * 6);
        gp[0] = make_float2(m[0], m[1]);
        gp[1] = make_float2(m[2], m[3]);
        gp[2] = make_float2(m[4], m[5]);
    }
}

// ---- pass 2: boundary scan + chunk replay + output writes (round-0 verbatim) ----
__global__ __launch_bounds__(256) void ekf_opass(
    const float* __restrict__ z, const float* __restrict__ u,
    const float* __restrict__ mean0, const float* __restrict__ coef,
    const float* __restrict__ Gmat, const float* __restrict__ g,
    float* __restrict__ out)
{
    const int c = blockIdx.y;
    const int b = blockIdx.x * 256 + threadIdx.x;

    float m[6];
    {
        const float2* mp = (const float2*)(mean0 + (size_t)b * 6);
        float2 a0 = mp[0], a1 = mp[1], a2 = mp[2];
        m[0]=a0.x; m[1]=a0.y; m[2]=a1.x; m[3]=a1.y; m[4]=a2.x; m[5]=a2.y;
    }

    for (int cc = 0; cc < c; ++cc) {
        const float* G = Gmat + cc * 36;            // uniform -> s_load
        const float2* gp = (const float2*)(g + ((size_t)cc * BATCH + b) * 6);
        float2 g01 = gp[0], g23 = gp[1], g45 = gp[2];
        float gv[6] = { g01.x, g01.y, g23.x, g23.y, g45.x, g45.y };
        float nm[6];
        #pragma unroll
        for (int i = 0; i < 6; ++i) {
            float s2 = gv[i];
            #pragma unroll
            for (int j = 0; j < 6; ++j) s2 += G[i*6+j] * m[j];
            nm[i] = s2;
        }
        #pragma unroll
        for (int i = 0; i < 6; ++i) m[i] = nm[i];
    }

    #pragma unroll
    for (int s = 0; s < CLEN; ++s) {
        const int t = c * CLEN + s;
        const float* cf = coef + t * NCOEF;         // uniform -> s_load
        const int base  = t * BATCH + b;

        const float*  zp = z + (size_t)base * 3;
        const float2* up = (const float2*)(u + (size_t)base * 6);
        float zz[3] = { zp[0], zp[1], zp[2] };
        float2 u01 = up[0], u23 = up[1], u45 = up[2];
        float uu[6] = { u01.x, u01.y, u23.x, u23.y, u45.x, u45.y };

        float nm[6];
        #pragma unroll
        for (int i = 0; i < 6; ++i) {
            float s2 = 0.f;
            #pragma unroll
            for (int j = 0; j < 6; ++j) s2 += cf[i*6+j] * m[j];
            #pragma unroll
            for (int j = 0; j < 6; ++j) s2 += cf[36 + i*6 + j] * uu[j];
            #pragma unroll
            for (int j = 0; j < 3; ++j) s2 += cf[72 + i*3 + j] * zz[j];
            nm[i] = s2;
        }

        float2* op = (float2*)(out + (size_t)base * 6);
        op[0] = make_float2(nm[0], nm[1]);
        op[1] = make_float2(nm[2], nm[3]);
        op[2] = make_float2(nm[4], nm[5]);

        #pragma unroll
        for (int i = 0; i < 6; ++i) m[i] = nm[i];
    }
}

// ---- standalone precompute (fallback path only; round-0 verbatim) ----
__global__ __launch_bounds__(64) void ekf_precompute(
    const float* __restrict__ cov0, const float* __restrict__ Ag,
    const float* __restrict__ Bg,   const float* __restrict__ Qtg,
    const float* __restrict__ Cg,   const float* __restrict__ Rtg,
    float* __restrict__ coef)
{
    __shared__ float sA[36], sB[36], sC[18], sQt[36], sRt[9];
    __shared__ float Qc[36], Rc[9];
    const int tid = threadIdx.x;

    if (tid < 36) { sA[tid] = Ag[tid]; sB[tid] = Bg[tid]; sQt[tid] = Qtg[tid]; }
    if (tid < 18) sC[tid] = Cg[tid];
    if (tid < 9)  sRt[tid] = Rtg[tid];
    __syncthreads();

    if (tid < 36) {
        int i = tid / 6, j = tid % 6; float s = 0.f;
        #pragma unroll
        for (int k = 0; k < 6; ++k) s += sQt[i*6+k] * sQt[j*6+k];
        Qc[tid] = s;
    } else if (tid < 45) {
        int q = tid - 36, i = q / 3, j = q % 3; float s = 0.f;
        #pragma unroll
        for (int k = 0; k < 3; ++k) s += sRt[i*3+k] * sRt[j*3+k];
        Rc[q] = s;
    }
    __syncthreads();

    const int i6 = tid / 6, j6 = tid % 6;
    const int i3 = tid / 3, j3 = tid % 3;
    const int qS = (tid >= 36 && tid < 45) ? tid - 36 : 0;
    const int sa = qS / 3, sb = qS % 3;

    float Ai[6], Aj[6], Acol[6], Bcol[6], Cst[18], Crow[6], Ca[6];
    float qcv = 0.f, rcv = 0.f;
    #pragma unroll
    for (int l = 0; l < 6; ++l) { Ai[l]=0.f; Aj[l]=0.f; Acol[l]=0.f; Bcol[l]=0.f; Crow[l]=0.f; Ca[l]=0.f; }
    #pragma unroll
    for (int l = 0; l < 18; ++l) Cst[l] = 0.f;

    if (tid < 36) {
        #pragma unroll
        for (int l = 0; l < 6; ++l) {
            Ai[l] = sA[i6*6+l]; Aj[l] = sA[j6*6+l];
            Acol[l] = sA[l*6+j6]; Bcol[l] = sB[l*6+j6];
        }
        #pragma unroll
        for (int l = 0; l < 18; ++l) Cst[l] = sC[l];
        qcv = Qc[tid];
    }
    if (tid < 18) {
        #pragma unroll
        for (int l = 0; l < 6; ++l) Crow[l] = sC[j3*6+l];
    }
    if (tid >= 36 && tid < 45) {
        #pragma unroll
        for (int l = 0; l < 6; ++l) Ca[l] = sC[sa*6+l];
        rcv = Rc[qS];
    }

    float Preg = 0.f;
    if (tid < 36) Preg = cov0[tid];
    __syncthreads();

    for (int t = 0; t < T_STEPS; ++t) {
        float Pf[36];
        #pragma unroll
        for (int e = 0; e < 36; ++e) Pf[e] = rdlane(Preg, e);
        float p1 = qcv;
        #pragma unroll
        for (int k = 0; k < 6; ++k) {
            float tmp = 0.f;
            #pragma unroll
            for (int l = 0; l < 6; ++l) tmp += Pf[k*6+l] * Aj[l];
            p1 += Ai[k] * tmp;
        }

        float p1r[6];
        #pragma unroll
        for (int l = 0; l < 6; ++l) p1r[l] = __shfl(p1, i3*6 + l);
        float pct = p1r[0]*Crow[0] + p1r[1]*Crow[1] + p1r[2]*Crow[2]
                  + p1r[3]*Crow[3] + p1r[4]*Crow[4] + p1r[5]*Crow[5];

        float sv = rcv;
        #pragma unroll
        for (int l = 0; l < 6; ++l) sv += Ca[l] * __shfl(pct, l*3 + sb);

        float a  = rdlane(sv, 36), b  = rdlane(sv, 37), c  = rdlane(sv, 38);
        float d  = rdlane(sv, 39), e  = rdlane(sv, 40), f  = rdlane(sv, 41);
        float g  = rdlane(sv, 42), h  = rdlane(sv, 43), i9 = rdlane(sv, 44);
        float idet = 1.0f / (a*(e*i9-f*h) - b*(d*i9-f*g) + c*(d*h-e*g));
        float s0 =  (e*i9-f*h)*idet, s1 = -(b*i9-c*h)*idet, s2 =  (b*f-c*e)*idet;
        float s3 = -(d*i9-f*g)*idet, s4 =  (a*i9-c*g)*idet, s5 = -(a*f-c*d)*idet;
        float s6 =  (d*h-e*g)*idet,  s7 = -(a*h-b*g)*idet,  s8 =  (a*e-b*d)*idet;

        float Pi0 = __shfl(pct, i6*3 + 0);
        float Pi1 = __shfl(pct, i6*3 + 1);
        float Pi2 = __shfl(pct, i6*3 + 2);
        float K0 = Pi0*s0 + Pi1*s3 + Pi2*s6;
        float K1 = Pi0*s1 + Pi1*s4 + Pi2*s7;
        float K2 = Pi0*s2 + Pi1*s5 + Pi2*s8;

        float ik[6];
        #pragma unroll
        for (int k = 0; k < 6; ++k)
            ik[k] = ((i6 == k) ? 1.f : 0.f)
                  - (K0*Cst[0*6+k] + K1*Cst[1*6+k] + K2*Cst[2*6+k]);

        float p1col[6];
        #pragma unroll
        for (int k = 0; k < 6; ++k) p1col[k] = __shfl(p1, k*6 + j6);

        float mo = 0.f, no = 0.f, pn = 0.f;
        #pragma unroll
        for (int k = 0; k < 6; ++k) {
            mo += ik[k] * Acol[k];
            no += ik[k] * Bcol[k];
            pn += ik[k] * p1col[k];
        }

        if (tid < 36) {
            coef[t*NCOEF + tid]      = mo;
            coef[t*NCOEF + 36 + tid] = no;
            if (j6 < 3)
                coef[t*NCOEF + 72 + i6*3 + j6] = (j6 == 0 ? K0 : (j6 == 1 ? K1 : K2));
        }
        Preg = pn;
    }
}

// ---- fallback mean kernel (round-0 verbatim, used if ws too small) ----
__global__ __launch_bounds__(128) void ekf_mean(
    const float* __restrict__ z, const float* __restrict__ u,
    const float* __restrict__ mean0, const float* __restrict__ coef,
    float* __restrict__ out)
{
    __shared__ float sc[T_STEPS * NCOEF];
    const int tid = threadIdx.x;
    for (int idx = tid; idx < T_STEPS * NCOEF; idx += 128) sc[idx] = coef[idx];

    const int b = blockIdx.x * 128 + tid;
    float m[6];
    {
        const float2* mp = (const float2*)(mean0 + b * 6);
        float2 a0 = mp[0], a1 = mp[1], a2 = mp[2];
        m[0]=a0.x; m[1]=a0.y; m[2]=a1.x; m[3]=a1.y; m[4]=a2.x; m[5]=a2.y;
    }
    __syncthreads();

    #pragma unroll 2
    for (int t = 0; t < T_STEPS; ++t) {
        const float* cf  = &sc[t * NCOEF];
        const int base   = t * BATCH + b;
        const float*  zp = z + base * 3;
        const float2* up = (const float2*)(u + (size_t)base * 6);

        float zz[3] = { zp[0], zp[1], zp[2] };
        float2 u01 = up[0], u23 = up[1], u45 = up[2];
        float uu[6] = { u01.x, u01.y, u23.x, u23.y, u45.x, u45.y };

        float nm[6];
        #pragma unroll
        for (int i = 0; i < 6; ++i) {
            float s = 0.f;
            #pragma unroll
            for (int j = 0; j < 6; ++j) s += cf[i*6+j] * m[j];
            #pragma unroll
            for (int j = 0; j < 6; ++j) s += cf[36 + i*6 + j] * uu[j];
            #pragma unroll
            for (int j = 0; j < 3; ++j) s += cf[72 + i*3 + j] * zz[j];
            nm[i] = s;
        }

        float2* op = (float2*)(out + (size_t)base * 6);
        op[0] = make_float2(nm[0], nm[1]);
        op[1] = make_float2(nm[2], nm[3]);
        op[2] = make_float2(nm[4], nm[5]);

        #pragma unroll
        for (int i = 0; i < 6; ++i) m[i] = nm[i];
    }
}

extern "C" void kernel_launch(void* const* d_in, const int* in_sizes, int n_in,
                              void* d_out, int out_size, void* d_ws, size_t ws_size,
                              hipStream_t stream) {
    const float* meas  = (const float*)d_in[0];
    const float* useq  = (const float*)d_in[1];
    const float* mean0 = (const float*)d_in[2];
    const float* cov0  = (const float*)d_in[3];
    const float* A     = (const float*)d_in[4];
    const float* Bm    = (const float*)d_in[5];
    const float* Qt    = (const float*)d_in[6];
    const float* C     = (const float*)d_in[7];
    const float* Rt    = (const float*)d_in[8];
    float* out  = (float*)d_out;

    float* coef = (float*)d_ws;                       // 23040 B
    float* Gmat = (float*)((char*)d_ws + G_OFF);      // 1152 B
    float* gvec = (float*)((char*)d_ws + GV_OFF);     // 6.29 MB

    if (ws_size >= (size_t)WS_NEED) {
        dim3 grid(BATCH / 256, NCHUNK);
        ekf_gfused<<<grid, 256, 0, stream>>>(meas, useq, cov0, A, Bm, Qt, C, Rt,
                                             coef, Gmat, gvec);
        ekf_opass<<<grid, 256, 0, stream>>>(meas, useq, mean0, coef, Gmat, gvec, out);
    } else if (ws_size >= (size_t)(T_STEPS * NCOEF * 4)) {
        float* coef2 = (float*)d_ws;
        ekf_precompute<<<1, 64, 0, stream>>>(cov0, A, Bm, Qt, C, Rt, coef2);
        ekf_mean<<<BATCH / 128, 128, 0, stream>>>(meas, useq, mean0, coef2, out);
    }
}

// Round 7
// 192.133 us; speedup vs baseline: 1.1163x; 1.1163x over previous
//
#include <hip/hip_runtime.h>

// ExtendedKalmanFilter: T=64, B=32768, D=6, O=3, U=6.
//
// cov0 is broadcast(0.1*I) and A,Bm,Q,C,R are shared => covariance/gain
// recursion is batch-independent. Kernel 1 (1 wave) runs it once, storing
// per-step affine coefficients  mean_{t+1} = M_t mean_t + N_t u_t + K_t z_t,
// plus chunk-composed transitions G_c = M_{c*8+7}...M_{c*8}. Kernels 2/3
// solve the linear mean recurrence as a chunked scan (8 chunks of 8):
// gpass computes chunk offsets from m=0; opass scans boundaries and
// replays chunks writing outputs. (Round-0 proven structure, 191.4 us.)
//
// Round-7 change (single variable): BITWISE FIXED-POINT EARLY EXIT in the
// Riccati loop. Rounds 1/2/5/6 proved intra-kernel overlap of the serial
// 46 us chain with throughput waves inflates the chain 1.7-2x (issue
// contention + launch_bounds-forced spills) - structural dead end. Instead:
// the fp32 Riccati iteration is a contraction here; once pn == Preg
// BITWISE on all 64 lanes, step t+1's inputs equal step t's, so by
// determinism all remaining M/N/K are bitwise equal to step t's. We
// ballot-check each step (~15 cyc) and on convergence break + fill
// coef[t+1..63]/Mall from held registers. coef is bit-identical to
// round-0 in BOTH branches => absmax stays exactly 0.0625. Downside
// bounded at +1% if the fixed point never fires.

#define T_STEPS 64
#define BATCH   32768
#define NCOEF   90   // per-step: M(36) + N(36) + K(18)
#define NCHUNK  8
#define CLEN    8

#define G_OFF   23040                      // bytes: after coef[64*90]
#define GV_OFF  24192                      // bytes: after Gmat[8*36]
#define WS_NEED (GV_OFF + NCHUNK * BATCH * 6 * 4)

__device__ __forceinline__ float rdlane(float v, int lane) {
    return __int_as_float(__builtin_amdgcn_readlane(__float_as_int(v), lane));
}

__global__ __launch_bounds__(64) void ekf_precompute(
    const float* __restrict__ cov0, const float* __restrict__ Ag,
    const float* __restrict__ Bg,   const float* __restrict__ Qtg,
    const float* __restrict__ Cg,   const float* __restrict__ Rtg,
    float* __restrict__ coef, float* __restrict__ Gmat, int writeG)
{
    __shared__ float sA[36], sB[36], sC[18], sQt[36], sRt[9];
    __shared__ float Qc[36], Rc[9];
    __shared__ float Mall[T_STEPS * 36];   // M_t log for the G-product phase
    const int tid = threadIdx.x;

    // ---- setup (once; LDS + barriers fine) ----
    if (tid < 36) { sA[tid] = Ag[tid]; sB[tid] = Bg[tid]; sQt[tid] = Qtg[tid]; }
    if (tid < 18) sC[tid] = Cg[tid];
    if (tid < 9)  sRt[tid] = Rtg[tid];
    __syncthreads();

    if (tid < 36) {                        // Qc = Qt Qt^T  (round-1 order)
        int i = tid / 6, j = tid % 6; float s = 0.f;
        #pragma unroll
        for (int k = 0; k < 6; ++k) s += sQt[i*6+k] * sQt[j*6+k];
        Qc[tid] = s;
    } else if (tid < 45) {                 // Rc = Rt Rt^T
        int q = tid - 36, i = q / 3, j = q % 3; float s = 0.f;
        #pragma unroll
        for (int k = 0; k < 3; ++k) s += sRt[i*3+k] * sRt[j*3+k];
        Rc[q] = s;
    }
    __syncthreads();

    // ---- hoist static operands into per-lane registers ----
    const int i6 = tid / 6, j6 = tid % 6;      // P/P1-owner coords (tid < 36)
    const int i3 = tid / 3, j3 = tid % 3;      // PCt-owner coords (tid < 18)
    const int qS = (tid >= 36 && tid < 45) ? tid - 36 : 0;   // S-owner coords
    const int sa = qS / 3, sb = qS % 3;

    float Ai[6], Aj[6], Acol[6], Bcol[6], Cst[18], Crow[6], Ca[6];
    float qcv = 0.f, rcv = 0.f;
    #pragma unroll
    for (int l = 0; l < 6; ++l) { Ai[l]=0.f; Aj[l]=0.f; Acol[l]=0.f; Bcol[l]=0.f; Crow[l]=0.f; Ca[l]=0.f; }
    #pragma unroll
    for (int l = 0; l < 18; ++l) Cst[l] = 0.f;

    if (tid < 36) {
        #pragma unroll
        for (int l = 0; l < 6; ++l) {
            Ai[l] = sA[i6*6+l]; Aj[l] = sA[j6*6+l];
            Acol[l] = sA[l*6+j6]; Bcol[l] = sB[l*6+j6];
        }
        #pragma unroll
        for (int l = 0; l < 18; ++l) Cst[l] = sC[l];
        qcv = Qc[tid];
    }
    if (tid < 18) {
        #pragma unroll
        for (int l = 0; l < 6; ++l) Crow[l] = sC[j3*6+l];
    }
    if (tid >= 36 && tid < 45) {
        #pragma unroll
        for (int l = 0; l < 6; ++l) Ca[l] = sC[sa*6+l];
        rcv = Rc[qS];
    }

    float Preg = 0.f;                      // lanes 0..35 own P[i6][j6]
    if (tid < 36) Preg = cov0[tid];
    __syncthreads();                       // Mall/LDS quiesce before loop

    // held outputs for the post-convergence fill
    float mo = 0.f, no = 0.f, K0 = 0.f, K1 = 0.f, K2 = 0.f;
    int tconv = T_STEPS;                   // first step whose coef is a copy

    for (int t = 0; t < T_STEPS; ++t) {
        // ---- stage A: P1 = A P A^T + Qc (round-0 verbatim) ----
        float Pf[36];
        #pragma unroll
        for (int e = 0; e < 36; ++e) Pf[e] = rdlane(Preg, e);
        float p1 = qcv;
        #pragma unroll
        for (int k = 0; k < 6; ++k) {
            float tmp = 0.f;
            #pragma unroll
            for (int l = 0; l < 6; ++l) tmp += Pf[k*6+l] * Aj[l];
            p1 += Ai[k] * tmp;
        }

        // ---- stage B1: PCt[i3][j3] = sum_l P1[i3][l] * C[j3][l] (lanes 0..17) ----
        float p1r[6];
        #pragma unroll
        for (int l = 0; l < 6; ++l) p1r[l] = __shfl(p1, i3*6 + l);
        float pct = p1r[0]*Crow[0] + p1r[1]*Crow[1] + p1r[2]*Crow[2]
                  + p1r[3]*Crow[3] + p1r[4]*Crow[4] + p1r[5]*Crow[5];

        // ---- stage B2: S[sa][sb] = Rc + sum_l C[sa][l]*PCt[l][sb] (lanes 36..44) ----
        float sv = rcv;
        #pragma unroll
        for (int l = 0; l < 6; ++l) sv += Ca[l] * __shfl(pct, l*3 + sb);

        // ---- stage C: inv(S), K, IKC, M/N/Pnext (round-0 verbatim math) ----
        float a  = rdlane(sv, 36), b  = rdlane(sv, 37), c  = rdlane(sv, 38);
        float d  = rdlane(sv, 39), e  = rdlane(sv, 40), f  = rdlane(sv, 41);
        float g  = rdlane(sv, 42), h  = rdlane(sv, 43), i9 = rdlane(sv, 44);
        float idet = 1.0f / (a*(e*i9-f*h) - b*(d*i9-f*g) + c*(d*h-e*g));
        float s0 =  (e*i9-f*h)*idet, s1 = -(b*i9-c*h)*idet, s2 =  (b*f-c*e)*idet;
        float s3 = -(d*i9-f*g)*idet, s4 =  (a*i9-c*g)*idet, s5 = -(a*f-c*d)*idet;
        float s6 =  (d*h-e*g)*idet,  s7 = -(a*h-b*g)*idet,  s8 =  (a*e-b*d)*idet;

        float Pi0 = __shfl(pct, i6*3 + 0);
        float Pi1 = __shfl(pct, i6*3 + 1);
        float Pi2 = __shfl(pct, i6*3 + 2);
        K0 = Pi0*s0 + Pi1*s3 + Pi2*s6;
        K1 = Pi0*s1 + Pi1*s4 + Pi2*s7;
        K2 = Pi0*s2 + Pi1*s5 + Pi2*s8;

        float ik[6];
        #pragma unroll
        for (int k = 0; k < 6; ++k)
            ik[k] = ((i6 == k) ? 1.f : 0.f)
                  - (K0*Cst[0*6+k] + K1*Cst[1*6+k] + K2*Cst[2*6+k]);

        float p1col[6];
        #pragma unroll
        for (int k = 0; k < 6; ++k) p1col[k] = __shfl(p1, k*6 + j6);

        float pn = 0.f;
        mo = 0.f; no = 0.f;
        #pragma unroll
        for (int k = 0; k < 6; ++k) {
            mo += ik[k] * Acol[k];
            no += ik[k] * Bcol[k];
            pn += ik[k] * p1col[k];
        }

        if (tid < 36) {
            coef[t*NCOEF + tid]      = mo;
            coef[t*NCOEF + 36 + tid] = no;
            if (j6 < 3)
                coef[t*NCOEF + 72 + i6*3 + j6] = (j6 == 0 ? K0 : (j6 == 1 ? K1 : K2));
            Mall[t*36 + tid] = mo;
        }

        // ---- bitwise fixed-point check: pn(t) == P(t) on every lane ----
        // (all lanes carry a deterministic pn recursion, so equality on all
        //  64 lanes => step t+1's inputs equal step t's => all remaining
        //  M/N/K are bitwise equal to this step's. Wave-uniform branch.)
        const bool fixedpt =
            (__ballot(pn == Preg) == 0xFFFFFFFFFFFFFFFFull);
        Preg = pn;                          // next P (lanes 0..35 meaningful)
        if (fixedpt) { tconv = t + 1; break; }
    }

    // ---- post-convergence fill: bit-exact copies of the last step ----
    for (int t = tconv; t < T_STEPS; ++t) {
        if (tid < 36) {
            coef[t*NCOEF + tid]      = mo;
            coef[t*NCOEF + 36 + tid] = no;
            if (j6 < 3)
                coef[t*NCOEF + 72 + i6*3 + j6] = (j6 == 0 ? K0 : (j6 == 1 ? K1 : K2));
            Mall[t*36 + tid] = mo;
        }
    }
    __syncthreads();                        // drain Mall writes before G phase

    // ---- G-product phase: G_c = M_{c*8+7} ... M_{c*8} (round-0 order) ----
    if (writeG) {
        const int im = (tid < 36) ? i6 : 0;           // clamp LDS index
        for (int cch = 0; cch < NCHUNK; ++cch) {
            float Gv = (tid < 36) ? Mall[(cch*CLEN)*36 + tid] : 0.f;
            for (int s = 1; s < CLEN; ++s) {
                float acc = 0.f;
                #pragma unroll
                for (int k = 0; k < 6; ++k) {
                    float gk = __shfl(Gv, k*6 + j6);
                    acc += Mall[(cch*CLEN + s)*36 + im*6 + k] * gk;
                }
                Gv = acc;
            }
            if (tid < 36) Gmat[cch*36 + tid] = Gv;
        }
    }
}

// ---- pass 1: per-chunk offset vectors g_c[b] (round-0 verbatim) ----
__global__ __launch_bounds__(256) void ekf_gpass(
    const float* __restrict__ z, const float* __restrict__ u,
    const float* __restrict__ coef, float* __restrict__ g)
{
    const int c = blockIdx.y;
    const int b = blockIdx.x * 256 + threadIdx.x;

    float m[6] = {0.f, 0.f, 0.f, 0.f, 0.f, 0.f};

    #pragma unroll
    for (int s = 0; s < CLEN; ++s) {
        const int t = c * CLEN + s;
        const float* cf = coef + t * NCOEF;        // uniform -> s_load
        const int base  = t * BATCH + b;

        const float*  zp = z + (size_t)base * 3;
        const float2* up = (const float2*)(u + (size_t)base * 6);
        float zz[3] = { zp[0], zp[1], zp[2] };
        float2 u01 = up[0], u23 = up[1], u45 = up[2];
        float uu[6] = { u01.x, u01.y, u23.x, u23.y, u45.x, u45.y };

        float nm[6];
        #pragma unroll
        for (int i = 0; i < 6; ++i) {               // round-1 accumulation order
            float s2 = 0.f;
            #pragma unroll
            for (int j = 0; j < 6; ++j) s2 += cf[i*6+j] * m[j];
            #pragma unroll
            for (int j = 0; j < 6; ++j) s2 += cf[36 + i*6 + j] * uu[j];
            #pragma unroll
            for (int j = 0; j < 3; ++j) s2 += cf[72 + i*3 + j] * zz[j];
            nm[i] = s2;
        }
        #pragma unroll
        for (int i = 0; i < 6; ++i) m[i] = nm[i];
    }

    float2* gp = (float2*)(g + ((size_t)c * BATCH + b) * 6);
    gp[0] = make_float2(m[0], m[1]);
    gp[1] = make_float2(m[2], m[3]);
    gp[2] = make_float2(m[4], m[5]);
}

// ---- pass 2: boundary scan + chunk replay + output writes (round-0 verbatim) ----
__global__ __launch_bounds__(256) void ekf_opass(
    const float* __restrict__ z, const float* __restrict__ u,
    const float* __restrict__ mean0, const float* __restrict__ coef,
    const float* __restrict__ Gmat, const float* __restrict__ g,
    float* __restrict__ out)
{
    const int c = blockIdx.y;
    const int b = blockIdx.x * 256 + threadIdx.x;

    float m[6];
    {
        const float2* mp = (const float2*)(mean0 + (size_t)b * 6);
        float2 a0 = mp[0], a1 = mp[1], a2 = mp[2];
        m[0]=a0.x; m[1]=a0.y; m[2]=a1.x; m[3]=a1.y; m[4]=a2.x; m[5]=a2.y;
    }

    for (int cc = 0; cc < c; ++cc) {
        const float* G = Gmat + cc * 36;            // uniform -> s_load
        const float2* gp = (const float2*)(g + ((size_t)cc * BATCH + b) * 6);
        float2 g01 = gp[0], g23 = gp[1], g45 = gp[2];
        float gv[6] = { g01.x, g01.y, g23.x, g23.y, g45.x, g45.y };
        float nm[6];
        #pragma unroll
        for (int i = 0; i < 6; ++i) {
            float s2 = gv[i];
            #pragma unroll
            for (int j = 0; j < 6; ++j) s2 += G[i*6+j] * m[j];
            nm[i] = s2;
        }
        #pragma unroll
        for (int i = 0; i < 6; ++i) m[i] = nm[i];
    }

    #pragma unroll
    for (int s = 0; s < CLEN; ++s) {
        const int t = c * CLEN + s;
        const float* cf = coef + t * NCOEF;         // uniform -> s_load
        const int base  = t * BATCH + b;

        const float*  zp = z + (size_t)base * 3;
        const float2* up = (const float2*)(u + (size_t)base * 6);
        float zz[3] = { zp[0], zp[1], zp[2] };
        float2 u01 = up[0], u23 = up[1], u45 = up[2];
        float uu[6] = { u01.x, u01.y, u23.x, u23.y, u45.x, u45.y };

        float nm[6];
        #pragma unroll
        for (int i = 0; i < 6; ++i) {
            float s2 = 0.f;
            #pragma unroll
            for (int j = 0; j < 6; ++j) s2 += cf[i*6+j] * m[j];
            #pragma unroll
            for (int j = 0; j < 6; ++j) s2 += cf[36 + i*6 + j] * uu[j];
            #pragma unroll
            for (int j = 0; j < 3; ++j) s2 += cf[72 + i*3 + j] * zz[j];
            nm[i] = s2;
        }

        float2* op = (float2*)(out + (size_t)base * 6);
        op[0] = make_float2(nm[0], nm[1]);
        op[1] = make_float2(nm[2], nm[3]);
        op[2] = make_float2(nm[4], nm[5]);

        #pragma unroll
        for (int i = 0; i < 6; ++i) m[i] = nm[i];
    }
}

// ---- fallback mean kernel (round-0 verbatim, used if ws too small) ----
__global__ __launch_bounds__(128) void ekf_mean(
    const float* __restrict__ z, const float* __restrict__ u,
    const float* __restrict__ mean0, const float* __restrict__ coef,
    float* __restrict__ out)
{
    __shared__ float sc[T_STEPS * NCOEF];
    const int tid = threadIdx.x;
    for (int idx = tid; idx < T_STEPS * NCOEF; idx += 128) sc[idx] = coef[idx];

    const int b = blockIdx.x * 128 + tid;
    float m[6];
    {
        const float2* mp = (const float2*)(mean0 + b * 6);
        float2 a0 = mp[0], a1 = mp[1], a2 = mp[2];
        m[0]=a0.x; m[1]=a0.y; m[2]=a1.x; m[3]=a1.y; m[4]=a2.x; m[5]=a2.y;
    }
    __syncthreads();

    #pragma unroll 2
    for (int t = 0; t < T_STEPS; ++t) {
        const float* cf  = &sc[t * NCOEF];
        const int base   = t * BATCH + b;
        const float*  zp = z + base * 3;
        const float2* up = (const float2*)(u + (size_t)base * 6);

        float zz[3] = { zp[0], zp[1], zp[2] };
        float2 u01 = up[0], u23 = up[1], u45 = up[2];
        float uu[6] = { u01.x, u01.y, u23.x, u23.y, u45.x, u45.y };

        float nm[6];
        #pragma unroll
        for (int i = 0; i < 6; ++i) {
            float s = 0.f;
            #pragma unroll
            for (int j = 0; j < 6; ++j) s += cf[i*6+j] * m[j];
            #pragma unroll
            for (int j = 0; j < 6; ++j) s += cf[36 + i*6 + j] * uu[j];
            #pragma unroll
            for (int j = 0; j < 3; ++j) s += cf[72 + i*3 + j] * zz[j];
            nm[i] = s;
        }

        float2* op = (float2*)(out + (size_t)base * 6);
        op[0] = make_float2(nm[0], nm[1]);
        op[1] = make_float2(nm[2], nm[3]);
        op[2] = make_float2(nm[4], nm[5]);

        #pragma unroll
        for (int i = 0; i < 6; ++i) m[i] = nm[i];
    }
}

extern "C" void kernel_launch(void* const* d_in, const int* in_sizes, int n_in,
                              void* d_out, int out_size, void* d_ws, size_t ws_size,
                              hipStream_t stream) {
    const float* meas  = (const float*)d_in[0];
    const float* useq  = (const float*)d_in[1];
    const float* mean0 = (const float*)d_in[2];
    const float* cov0  = (const float*)d_in[3];
    const float* A     = (const float*)d_in[4];
    const float* Bm    = (const float*)d_in[5];
    const float* Qt    = (const float*)d_in[6];
    const float* C     = (const float*)d_in[7];
    const float* Rt    = (const float*)d_in[8];
    float* out  = (float*)d_out;

    float* coef = (float*)d_ws;                       // 23040 B
    float* Gmat = (float*)((char*)d_ws + G_OFF);      // 1152 B
    float* gvec = (float*)((char*)d_ws + GV_OFF);     // 6.29 MB

    const bool scan_path = (ws_size >= (size_t)WS_NEED);

    ekf_precompute<<<1, 64, 0, stream>>>(cov0, A, Bm, Qt, C, Rt, coef, Gmat,
                                         scan_path ? 1 : 0);
    if (scan_path) {
        dim3 grid(BATCH / 256, NCHUNK);
        ekf_gpass<<<grid, 256, 0, stream>>>(meas, useq, coef, gvec);
        ekf_opass<<<grid, 256, 0, stream>>>(meas, useq, mean0, coef, Gmat, gvec, out);
    } else {
        ekf_mean<<<BATCH / 128, 128, 0, stream>>>(meas, useq, mean0, coef, out);
    }
}